// Round 7
// baseline (13020.876 us; speedup 1.0000x reference)
//
#include <hip/hip_runtime.h>
#include <hip/hip_bf16.h>

// ---------------- problem constants ----------------
constexpr int B_   = 16;
constexpr int L_   = 1024;
constexpr int S_   = 1023;      // L-1
constexpr int D_   = 768;
constexpr int H_   = 8;
constexpr int DH_  = 512;       // D/3*2
constexpr int HID_ = 256;
constexpr int FF_  = 3072;
constexpr int NA_  = 10000;
constexpr int NCATE_ = 4;
constexpr int NCONT_ = 6;
constexpr float EPS_ = 1e-5f;
constexpr long BSR_ = (long)B_ * S_;    // 16368 rows
constexpr int SLD_ = 1024;              // padded score leading dim (float4 alignment)

// workspace layout (floats) — total 58,712,064 floats = 234,848,256 B ≈ 224 MiB
constexpr long COMB_SZ = BSR_ * HID_;          //  4,190,208
constexpr long IDX_PAD = 49152;                //  3*BSR ints rounded up
constexpr long QKV_SZ  = BSR_ * DH_;           //  8,380,416
constexpr long SC_SZ   = (long)B_ * S_ * SLD_; // 16,760,832
constexpr long ZO_SZ   = BSR_ * D_;            // 12,570,624
constexpr size_t WS_NEED_BYTES =
    (size_t)(COMB_SZ + IDX_PAD + 3 * QKV_SZ + SC_SZ + ZO_SZ) * 4;

// ---------------- block reductions ----------------
__device__ __forceinline__ float blk_reduce_sum(float v, float* sm) {
#pragma unroll
    for (int off = 32; off > 0; off >>= 1) v += __shfl_down(v, off, 64);
    const int lane = threadIdx.x & 63, wv = threadIdx.x >> 6;
    if (lane == 0) sm[wv] = v;
    __syncthreads();
    float t = (threadIdx.x < 4) ? sm[threadIdx.x] : 0.f;
    t += __shfl_down(t, 2, 64);
    t += __shfl_down(t, 1, 64);
    if (threadIdx.x == 0) sm[4] = t;
    __syncthreads();
    float r = sm[4];
    __syncthreads();
    return r;
}

__device__ __forceinline__ float blk_reduce_max(float v, float* sm) {
#pragma unroll
    for (int off = 32; off > 0; off >>= 1) v = fmaxf(v, __shfl_down(v, off, 64));
    const int lane = threadIdx.x & 63, wv = threadIdx.x >> 6;
    if (lane == 0) sm[wv] = v;
    __syncthreads();
    float t = (threadIdx.x < 4) ? sm[threadIdx.x] : -3.4e38f;
    t = fmaxf(t, __shfl_down(t, 2, 64));
    t = fmaxf(t, __shfl_down(t, 1, 64));
    if (threadIdx.x == 0) sm[4] = t;
    __syncthreads();
    float r = sm[4];
    __syncthreads();
    return r;
}

// ---------------- ws-too-small sentinel ----------------
__global__ __launch_bounds__(256) void sentinel_k(float* __restrict__ out, int n)
{
    const int i = blockIdx.x * 256 + threadIdx.x;
    if (i < n) out[i] = 1e30f;   // unmistakable absmax signature
}

// ---------------- prep: row indices + comb ----------------
// yArr[r]  = cate_x[b,s,0] + targets[b,s]*NA        (M_emb row)
// nxArr[r] = cate_x[b,s+1,0]                        (E_emb / cate_emb row)
// sArr[r]  = s                                      (pos_emb row)
// comb[r]  = cate_emb[nx] + cont_x[b,s+1] @ cont_W + cont_b   (HID cols)
__global__ __launch_bounds__(256) void prep_k(
    const int* __restrict__ cate_x, const float* __restrict__ cont_x,
    const int* __restrict__ targets,
    const float* __restrict__ cate_emb, const float* __restrict__ cont_W,
    const float* __restrict__ cont_b,
    int* __restrict__ yArr, int* __restrict__ nxArr, int* __restrict__ sArr,
    float* __restrict__ comb)
{
    const int row = blockIdx.x;          // b*S + s
    const int b = row / S_;
    const int s = row - b * S_;
    const int nx = cate_x[((long)b * L_ + s + 1) * NCATE_];
    if (threadIdx.x == 0) {
        yArr[row]  = cate_x[((long)b * L_ + s) * NCATE_] + targets[(long)b * L_ + s] * NA_;
        nxArr[row] = nx;
        sArr[row]  = s;
    }
    const float* cx = cont_x + ((long)b * L_ + s + 1) * NCONT_;
    float cv[NCONT_];
#pragma unroll
    for (int i = 0; i < NCONT_; ++i) cv[i] = cx[i];
    const int j = threadIdx.x;           // HID_==256 == blockDim.x
    float acc = cont_b[j];
#pragma unroll
    for (int i = 0; i < NCONT_; ++i) acc = fmaf(cv[i], cont_W[i * HID_ + j], acc);
    comb[(long)row * HID_ + j] = cate_emb[(long)nx * HID_ + j] + acc;
}

// ---------------- tiled fp32 GEMM with fused gather-A ----------------
// AMODE 0: A is a plain M x Kd row-major matrix (lda)
// AMODE 1: A-row r = M_emb[yArr[r]] + pos_emb[sArr[r]]   (Kd = 768)
// AMODE 2: A-row r = concat(E_emb[nxArr[r]], comb[r])    (Kd = 1024)
// C[bz] = alpha * A[bz] @ B[bz](^T) (+bias) (+Cadd) (relu?); ACCUM: C +=
// 128x128 tile, BK=16, 256 threads, 8x8 per thread.
template<int AMODE, bool TB, bool BIAS, bool RELU, bool ADDC, bool ACCUM>
__global__ __launch_bounds__(256) void sgemm_k(
    const float* __restrict__ A, const float* __restrict__ A2,
    const int* __restrict__ rIdx, const int* __restrict__ rS,
    const float* __restrict__ Bm,
    const float* __restrict__ bias, const float* __restrict__ Cadd,
    float* __restrict__ C,
    int M, int N, int Kd, int lda, int ldb, int ldc,
    long sA, long sB, long sC, float alpha)
{
    constexpr int BM = 128, BN = 128, BK = 16;
    __shared__ float As[BK][BM];
    __shared__ float Bs[BK][BN];

    const int tid = threadIdx.x;
    const int tx = tid & 15;     // col group (8 cols)
    const int ty = tid >> 4;     // row group (8 rows)
    const int rowBase = blockIdx.y * BM;
    const int colBase = blockIdx.x * BN;
    const int bz = blockIdx.z;
    if constexpr (AMODE == 0) A += (long)bz * sA;
    Bm += (long)bz * sB;
    C += (long)bz * sC;
    if constexpr (ADDC) Cadd += (long)bz * sC;

    float acc[8][8];
#pragma unroll
    for (int i = 0; i < 8; ++i)
#pragma unroll
        for (int j = 0; j < 8; ++j) acc[i][j] = 0.f;

    for (int k0 = 0; k0 < Kd; k0 += BK) {
        // ---- load A tile: 128 rows x 16 k ----
#pragma unroll
        for (int u = 0; u < 2; ++u) {
            const int f = tid + u * 256;      // float4 id 0..511
            const int r = f >> 2;             // 0..127
            const int k4 = (f & 3) * 4;       // 0,4,8,12
            const int gk = k0 + k4;
            float v0 = 0.f, v1 = 0.f, v2 = 0.f, v3 = 0.f;
            const int gr = rowBase + r;
            if (gr < M) {
                if constexpr (AMODE == 0) {
                    const float* p = A + (long)gr * lda + gk;
                    if (gk + 3 < Kd) {
                        float4 v = *(const float4*)p;
                        v0 = v.x; v1 = v.y; v2 = v.z; v3 = v.w;
                    } else {
                        if (gk + 0 < Kd) v0 = p[0];
                        if (gk + 1 < Kd) v1 = p[1];
                        if (gk + 2 < Kd) v2 = p[2];
                        if (gk + 3 < Kd) v3 = p[3];
                    }
                } else if constexpr (AMODE == 1) {
                    // M_hat row: M_emb[y] + pos_emb[s]; Kd==768, no tail
                    const int y = rIdx[gr];
                    const int s = rS[gr];
                    const float4 a = *(const float4*)(A  + (long)y * D_ + gk);
                    const float4 p = *(const float4*)(A2 + (long)s * D_ + gk);
                    v0 = a.x + p.x; v1 = a.y + p.y; v2 = a.z + p.z; v3 = a.w + p.w;
                } else {
                    // E_hat row: [E_emb[nx] | comb[r]]; Kd==1024, no tail.
                    // 768 is a multiple of 4, so a float4 never straddles it.
                    if (gk < D_) {
                        const int nx = rIdx[gr];
                        const float4 a = *(const float4*)(A + (long)nx * D_ + gk);
                        v0 = a.x; v1 = a.y; v2 = a.z; v3 = a.w;
                    } else {
                        const float4 a = *(const float4*)(A2 + (long)gr * HID_ + (gk - D_));
                        v0 = a.x; v1 = a.y; v2 = a.z; v3 = a.w;
                    }
                }
            }
            As[k4 + 0][r] = v0; As[k4 + 1][r] = v1;
            As[k4 + 2][r] = v2; As[k4 + 3][r] = v3;
        }
        // ---- load B tile ----
        if constexpr (!TB) {
            // Bm is Kd x N row-major
#pragma unroll
            for (int u = 0; u < 2; ++u) {
                const int f = tid + u * 256;
                const int kk = f >> 5;            // 0..15
                const int n4 = (f & 31) * 4;      // 0..124
                float v0 = 0.f, v1 = 0.f, v2 = 0.f, v3 = 0.f;
                const int gk = k0 + kk;
                const int gc = colBase + n4;
                if (gk < Kd) {
                    const float* p = Bm + (long)gk * ldb + gc;
                    if (gc + 3 < N) {
                        float4 v = *(const float4*)p;
                        v0 = v.x; v1 = v.y; v2 = v.z; v3 = v.w;
                    } else {
                        if (gc + 0 < N) v0 = p[0];
                        if (gc + 1 < N) v1 = p[1];
                        if (gc + 2 < N) v2 = p[2];
                        if (gc + 3 < N) v3 = p[3];
                    }
                }
                Bs[kk][n4 + 0] = v0; Bs[kk][n4 + 1] = v1;
                Bs[kk][n4 + 2] = v2; Bs[kk][n4 + 3] = v3;
            }
        } else {
            // Bm is N x Kd row-major (use rows as output cols)
#pragma unroll
            for (int u = 0; u < 2; ++u) {
                const int f = tid + u * 256;
                const int n = f >> 2;             // 0..127
                const int k4 = (f & 3) * 4;
                float v0 = 0.f, v1 = 0.f, v2 = 0.f, v3 = 0.f;
                const int gn = colBase + n;
                if (gn < N) {
                    const float* p = Bm + (long)gn * ldb + k0 + k4;
                    if (k0 + k4 + 3 < Kd) {
                        float4 v = *(const float4*)p;
                        v0 = v.x; v1 = v.y; v2 = v.z; v3 = v.w;
                    } else {
                        if (k0 + k4 + 0 < Kd) v0 = p[0];
                        if (k0 + k4 + 1 < Kd) v1 = p[1];
                        if (k0 + k4 + 2 < Kd) v2 = p[2];
                        if (k0 + k4 + 3 < Kd) v3 = p[3];
                    }
                }
                Bs[k4 + 0][n] = v0; Bs[k4 + 1][n] = v1;
                Bs[k4 + 2][n] = v2; Bs[k4 + 3][n] = v3;
            }
        }
        __syncthreads();

#pragma unroll
        for (int kk = 0; kk < BK; ++kk) {
            float a[8], b[8];
            *(float4*)&a[0] = *(const float4*)&As[kk][ty * 8];
            *(float4*)&a[4] = *(const float4*)&As[kk][ty * 8 + 4];
            *(float4*)&b[0] = *(const float4*)&Bs[kk][tx * 8];
            *(float4*)&b[4] = *(const float4*)&Bs[kk][tx * 8 + 4];
#pragma unroll
            for (int i = 0; i < 8; ++i)
#pragma unroll
                for (int j = 0; j < 8; ++j)
                    acc[i][j] = fmaf(a[i], b[j], acc[i][j]);
        }
        __syncthreads();
    }

    // ---- epilogue ----
#pragma unroll
    for (int i = 0; i < 8; ++i) {
        const int r = rowBase + ty * 8 + i;
        if (r >= M) continue;
#pragma unroll
        for (int j = 0; j < 8; ++j) {
            const int c = colBase + tx * 8 + j;
            if (c >= N) continue;
            float v = acc[i][j] * alpha;
            if constexpr (BIAS) v += bias[c];
            if constexpr (ADDC) v += Cadd[(long)r * ldc + c];
            if constexpr (RELU) v = fmaxf(v, 0.f);
            const long idx = (long)r * ldc + c;
            if constexpr (ACCUM) C[idx] += v; else C[idx] = v;
        }
    }
}

// ---------------- softmax over key axis with batch-index mask ----------------
// row = b*S + q ; keys k < b-1 get -1e5 added (reference's triu(B,S) mask)
__global__ __launch_bounds__(256) void softmax_k(float* __restrict__ Sc)
{
    const int row = blockIdx.x;
    const int b = row / S_;
    float* s = Sc + (long)row * SLD_;
    __shared__ float buf[S_];
    __shared__ float sm[5];
    const int klo = b - 1;     // keys below this are masked

    float m = -3.4e38f;
    for (int k = threadIdx.x; k < S_; k += 256) {
        float v = s[k];
        if (k < klo) v -= 1e5f;
        buf[k] = v;
        m = fmaxf(m, v);
    }
    m = blk_reduce_max(m, sm);
    float sum = 0.f;
    for (int k = threadIdx.x; k < S_; k += 256) {
        const float e = __expf(buf[k] - m);
        buf[k] = e;
        sum += e;
    }
    sum = blk_reduce_sum(sum, sm);
    const float inv = 1.0f / sum;
    for (int k = threadIdx.x; k < S_; k += 256) s[k] = buf[k] * inv;
}

// ---------------- layernorm + final projection ----------------
__global__ __launch_bounds__(256) void final_k(
    const float* __restrict__ h, const float* __restrict__ g,
    const float* __restrict__ bt, const float* __restrict__ fw,
    const float* __restrict__ fb, float* __restrict__ out)
{
    const int row = blockIdx.x;
    const float* hr = h + (long)row * D_;
    __shared__ float sm[5];

    float lsum = 0.f;
    for (int d = threadIdx.x; d < D_; d += 256) lsum += hr[d];
    const float mu = blk_reduce_sum(lsum, sm) * (1.0f / D_);

    float lvar = 0.f;
    for (int d = threadIdx.x; d < D_; d += 256) {
        const float t = hr[d] - mu;
        lvar = fmaf(t, t, lvar);
    }
    const float var = blk_reduce_sum(lvar, sm) * (1.0f / D_);
    const float rstd = 1.0f / sqrtf(var + EPS_);

    float ldot = 0.f;
    for (int d = threadIdx.x; d < D_; d += 256) {
        const float zn = (hr[d] - mu) * rstd * g[d] + bt[d];
        ldot = fmaf(zn, fw[d], ldot);
    }
    const float dot = blk_reduce_sum(ldot, sm);
    if (threadIdx.x == 0) out[row] = dot + fb[0];
}

// ---------------- host launch ----------------
static inline dim3 gemm_grid(int M, int N, int batch) {
    return dim3((N + 127) / 128, (M + 127) / 128, batch);
}

extern "C" void kernel_launch(void* const* d_in, const int* in_sizes, int n_in,
                              void* d_out, int out_size, void* d_ws, size_t ws_size,
                              hipStream_t stream)
{
    float* out = (float*)d_out;

    // ---- ws tripwire: if scratch is smaller than the arena, emit a sentinel
    // output (absmax ~1e30) instead of faulting. Deterministic across calls.
    if (ws_size < WS_NEED_BYTES) {
        sentinel_k<<<(out_size + 255) / 256, 256, 0, stream>>>(out, out_size);
        return;
    }

    const int*   cate_x   = (const int*)  d_in[0];
    const float* cont_x   = (const float*)d_in[1];
    /* d_in[2] = mask : unused by reference */
    const int*   targets  = (const int*)  d_in[3];
    const float* M_emb    = (const float*)d_in[4];
    const float* E_emb    = (const float*)d_in[5];
    const float* pos_emb  = (const float*)d_in[6];
    const float* cate_emb = (const float*)d_in[7];
    const float* cont_W   = (const float*)d_in[8];
    const float* cont_b   = (const float*)d_in[9];
    const float* WQ = (const float*)d_in[10];
    const float* bQ = (const float*)d_in[11];
    const float* WK = (const float*)d_in[12];
    const float* bK = (const float*)d_in[13];
    const float* WV = (const float*)d_in[14];
    const float* bV = (const float*)d_in[15];
    const float* W0 = (const float*)d_in[16];
    const float* ln_g = (const float*)d_in[17];
    const float* ln_b = (const float*)d_in[18];
    const float* W1 = (const float*)d_in[19];
    const float* b1 = (const float*)d_in[20];
    const float* W2 = (const float*)d_in[21];
    const float* b2 = (const float*)d_in[22];
    const float* fw = (const float*)d_in[23];
    const float* fb = (const float*)d_in[24];
    float* ws  = (float*)d_ws;

    // workspace arena (~224 MiB)
    float* comb  = ws;                                  // COMB_SZ
    int*   yArr  = (int*)(ws + COMB_SZ);                // BSR
    int*   nxArr = yArr + BSR_;                         // BSR
    int*   sArr  = nxArr + BSR_;                        // BSR (IDX_PAD total)
    float* Qh = ws + COMB_SZ + IDX_PAD;                 // QKV_SZ
    float* Kh = Qh + QKV_SZ;                            // QKV_SZ
    float* Vh = Kh + QKV_SZ;                            // QKV_SZ
    float* Sc = Vh + QKV_SZ;                            // SC_SZ
    float* Zo = Sc + SC_SZ;                             // ZO_SZ
    float* Zh   = Qh;   // alias: Q dead after QK^T
    float* Hid  = Qh;   // alias (FFN phase): BSR*768 fits in Qh+Kh span
    float* Hbuf = Sc;   // alias (FFN phase): BSR*768 fits in Sc span

    // 1) prep: indices + comb
    prep_k<<<(int)BSR_, 256, 0, stream>>>(cate_x, cont_x, targets, cate_emb,
                                          cont_W, cont_b, yArr, nxArr, sArr, comb);

    const float inv_sqrt_dh = 0.044194173824159216f;   // 1/sqrt(512)

    // 2) per-head attention; z accumulated across heads
    for (int h = 0; h < H_; ++h) {
        // Q = M_hat @ WQ[h] + bQ[h]   (gather-A mode 1)
        sgemm_k<1, false, true, false, false, false><<<gemm_grid((int)BSR_, DH_, 1), 256, 0, stream>>>(
            M_emb, pos_emb, yArr, sArr,
            WQ + (long)h * D_ * DH_, bQ + (long)h * DH_, nullptr, Qh,
            (int)BSR_, DH_, D_, D_, DH_, DH_, 0, 0, 0, 1.0f);
        // K = E_hat @ WK[h] + bK[h]   (gather-A mode 2)
        sgemm_k<2, false, true, false, false, false><<<gemm_grid((int)BSR_, DH_, 1), 256, 0, stream>>>(
            E_emb, comb, nxArr, nullptr,
            WK + (long)h * (D_ + HID_) * DH_, bK + (long)h * DH_, nullptr, Kh,
            (int)BSR_, DH_, D_ + HID_, 0, DH_, DH_, 0, 0, 0, 1.0f);
        // V = E_hat @ WV[h] + bV[h]
        sgemm_k<2, false, true, false, false, false><<<gemm_grid((int)BSR_, DH_, 1), 256, 0, stream>>>(
            E_emb, comb, nxArr, nullptr,
            WV + (long)h * (D_ + HID_) * DH_, bV + (long)h * DH_, nullptr, Vh,
            (int)BSR_, DH_, D_ + HID_, 0, DH_, DH_, 0, 0, 0, 1.0f);
        // scores = (1/sqrt(DH)) * Q @ K^T   (batched over b)
        sgemm_k<0, true, false, false, false, false><<<gemm_grid(S_, S_, B_), 256, 0, stream>>>(
            Qh, nullptr, nullptr, nullptr,
            Kh, nullptr, nullptr, Sc,
            S_, S_, DH_, DH_, DH_, SLD_,
            (long)S_ * DH_, (long)S_ * DH_, (long)S_ * SLD_, inv_sqrt_dh);
        // softmax rows (with batch-index mask)
        softmax_k<<<(int)BSR_, 256, 0, stream>>>(Sc);
        // Z = P @ V (batched over b); writes Zh (aliases dead Qh)
        sgemm_k<0, false, false, false, false, false><<<gemm_grid(S_, DH_, B_), 256, 0, stream>>>(
            Sc, nullptr, nullptr, nullptr,
            Vh, nullptr, nullptr, Zh,
            S_, DH_, S_, SLD_, DH_, DH_,
            (long)S_ * SLD_, (long)S_ * DH_, (long)S_ * DH_, 1.0f);
        // z (+)= Z_h @ W0[h*DH:(h+1)*DH, :]
        if (h == 0)
            sgemm_k<0, false, false, false, false, false><<<gemm_grid((int)BSR_, D_, 1), 256, 0, stream>>>(
                Zh, nullptr, nullptr, nullptr,
                W0 + (long)h * DH_ * D_, nullptr, nullptr, Zo,
                (int)BSR_, D_, DH_, DH_, D_, D_, 0, 0, 0, 1.0f);
        else
            sgemm_k<0, false, false, false, false, true><<<gemm_grid((int)BSR_, D_, 1), 256, 0, stream>>>(
                Zh, nullptr, nullptr, nullptr,
                W0 + (long)h * DH_ * D_, nullptr, nullptr, Zo,
                (int)BSR_, D_, DH_, DH_, D_, D_, 0, 0, 0, 1.0f);
    }

    // 3) FFN in 4 chunks of FF: h = relu(z@W1+b1)@W2 + b2 + z
    for (int c = 0; c < 4; ++c) {
        const int f0 = c * 768;
        // Hid = relu(z @ W1[:, f0:f0+768] + b1[f0:])
        sgemm_k<0, false, true, true, false, false><<<gemm_grid((int)BSR_, 768, 1), 256, 0, stream>>>(
            Zo, nullptr, nullptr, nullptr,
            W1 + f0, b1 + f0, nullptr, Hid,
            (int)BSR_, 768, D_, D_, FF_, 768, 0, 0, 0, 1.0f);
        if (c == 0)
            // Hbuf = Hid @ W2[f0:f0+768, :] + b2 + z
            sgemm_k<0, false, true, false, true, false><<<gemm_grid((int)BSR_, D_, 1), 256, 0, stream>>>(
                Hid, nullptr, nullptr, nullptr,
                W2 + (long)f0 * D_, b2, Zo, Hbuf,
                (int)BSR_, D_, 768, 768, D_, D_, 0, 0, 0, 1.0f);
        else
            // Hbuf += Hid @ W2[f0:f0+768, :]
            sgemm_k<0, false, false, false, false, true><<<gemm_grid((int)BSR_, D_, 1), 256, 0, stream>>>(
                Hid, nullptr, nullptr, nullptr,
                W2 + (long)f0 * D_, nullptr, nullptr, Hbuf,
                (int)BSR_, D_, 768, 768, D_, D_, 0, 0, 0, 1.0f);
    }

    // 4) layernorm + final projection
    final_k<<<(int)BSR_, 256, 0, stream>>>(Hbuf, ln_g, ln_b, fw, fb, out);

    (void)in_sizes; (void)n_in;
}

// Round 8
// 12930.873 us; speedup vs baseline: 1.0070x; 1.0070x over previous
//
#include <hip/hip_runtime.h>
#include <hip/hip_bf16.h>

// ---------------- problem constants ----------------
constexpr int B_   = 16;
constexpr int L_   = 1024;
constexpr int S_   = 1023;      // L-1
constexpr int D_   = 768;
constexpr int H_   = 8;
constexpr int DH_  = 512;       // D/3*2
constexpr int HID_ = 256;
constexpr int FF_  = 3072;
constexpr int NA_  = 10000;
constexpr int NCATE_ = 4;
constexpr int NCONT_ = 6;
constexpr float EPS_ = 1e-5f;
constexpr long BSR_ = (long)B_ * S_;    // 16368 rows
constexpr int SLD_ = 1024;              // padded score leading dim

// workspace layout (floats) — total 58,712,064 floats ≈ 224 MiB (known-good)
constexpr long COMB_SZ = BSR_ * HID_;
constexpr long IDX_PAD = 49152;
constexpr long QKV_SZ  = BSR_ * DH_;
constexpr long SC_SZ   = (long)B_ * S_ * SLD_;
constexpr long ZO_SZ   = BSR_ * D_;
constexpr size_t WS_NEED_BYTES =
    (size_t)(COMB_SZ + IDX_PAD + 3 * QKV_SZ + SC_SZ + ZO_SZ) * 4;

// ---------------- block reductions ----------------
__device__ __forceinline__ float blk_reduce_sum(float v, float* sm) {
#pragma unroll
    for (int off = 32; off > 0; off >>= 1) v += __shfl_down(v, off, 64);
    const int lane = threadIdx.x & 63, wv = threadIdx.x >> 6;
    if (lane == 0) sm[wv] = v;
    __syncthreads();
    float t = (threadIdx.x < 4) ? sm[threadIdx.x] : 0.f;
    t += __shfl_down(t, 2, 64);
    t += __shfl_down(t, 1, 64);
    if (threadIdx.x == 0) sm[4] = t;
    __syncthreads();
    float r = sm[4];
    __syncthreads();
    return r;
}

__device__ __forceinline__ float blk_reduce_max(float v, float* sm) {
#pragma unroll
    for (int off = 32; off > 0; off >>= 1) v = fmaxf(v, __shfl_down(v, off, 64));
    const int lane = threadIdx.x & 63, wv = threadIdx.x >> 6;
    if (lane == 0) sm[wv] = v;
    __syncthreads();
    float t = (threadIdx.x < 4) ? sm[threadIdx.x] : -3.4e38f;
    t = fmaxf(t, __shfl_down(t, 2, 64));
    t = fmaxf(t, __shfl_down(t, 1, 64));
    if (threadIdx.x == 0) sm[4] = t;
    __syncthreads();
    float r = sm[4];
    __syncthreads();
    return r;
}

// ---------------- ws-too-small sentinel ----------------
__global__ __launch_bounds__(256) void sentinel_k(float* __restrict__ out, int n)
{
    const int i = blockIdx.x * 256 + threadIdx.x;
    if (i < n) out[i] = 1e30f;
}

// ---------------- prep: row indices + comb ----------------
__global__ __launch_bounds__(256) void prep_k(
    const int* __restrict__ cate_x, const float* __restrict__ cont_x,
    const int* __restrict__ targets,
    const float* __restrict__ cate_emb, const float* __restrict__ cont_W,
    const float* __restrict__ cont_b,
    int* __restrict__ yArr, int* __restrict__ nxArr, int* __restrict__ sArr,
    float* __restrict__ comb)
{
    const int row = blockIdx.x;          // b*S + s
    const int b = row / S_;
    const int s = row - b * S_;
    const int nx = cate_x[((long)b * L_ + s + 1) * NCATE_];
    if (threadIdx.x == 0) {
        yArr[row]  = cate_x[((long)b * L_ + s) * NCATE_] + targets[(long)b * L_ + s] * NA_;
        nxArr[row] = nx;
        sArr[row]  = s;
    }
    const float* cx = cont_x + ((long)b * L_ + s + 1) * NCONT_;
    float cv[NCONT_];
#pragma unroll
    for (int i = 0; i < NCONT_; ++i) cv[i] = cx[i];
    const int j = threadIdx.x;
    float acc = cont_b[j];
#pragma unroll
    for (int i = 0; i < NCONT_; ++i) acc = fmaf(cv[i], cont_W[i * HID_ + j], acc);
    comb[(long)row * HID_ + j] = cate_emb[(long)nx * HID_ + j] + acc;
}

// ---------------- tiled fp32 GEMM, tile size TSZ in {64,128} ----------------
// AMODE 0: plain A (lda);  1: A-row = M_emb[yArr[r]] + pos_emb[sArr[r]] (Kd=768)
//                          2: A-row = [E_emb[nxArr[r]] | comb[r]]       (Kd=1024)
// KVF: blocks with colBase>=DH_ switch to {Bm2, bias2, C2} (fused K|V dispatch).
// Per-thread micro-tile TM x TM (TM=TSZ/16), split as 4-wide groups 64 apart
// (stride-16B fragment reads -> 2-way LDS bank aliasing, free on CDNA4).
template<int TSZ, int AMODE, bool TB, bool BIAS, bool RELU, bool ADDC, bool ACCUM, bool KVF>
__global__ __launch_bounds__(256) void sgemm_k(
    const float* __restrict__ A, const float* __restrict__ A2,
    const int* __restrict__ rIdx, const int* __restrict__ rS,
    const float* __restrict__ Bm, const float* __restrict__ Bm2,
    const float* __restrict__ bias, const float* __restrict__ bias2,
    const float* __restrict__ Cadd, float* __restrict__ C, float* __restrict__ C2,
    int M, int N, int Kd, int lda, int ldb, int ldc,
    long sA, long sB, long sC, float alpha)
{
    constexpr int BK = 16;
    constexpr int TM = TSZ / 16;            // 8 or 4
    constexpr int NL = TSZ / 64;            // f4 loads per thread per tile: 2 or 1
    constexpr int NF4M = TSZ / 4 - 1;
    constexpr int SHB  = (TSZ == 128) ? 5 : 4;
    __shared__ float As[BK][TSZ];
    __shared__ float Bs[BK][TSZ];

    const int tid = threadIdx.x;
    const int tx = tid & 15;
    const int ty = tid >> 4;
    const int rowBase = blockIdx.y * TSZ;
    int colBase = blockIdx.x * TSZ;
    const int bz = blockIdx.z;

    if constexpr (KVF) {
        if (colBase >= DH_) {
            Bm = Bm2;
            if constexpr (BIAS) bias = bias2;
            C = C2;
            colBase -= DH_;
        }
    }
    if constexpr (AMODE == 0) A += (long)bz * sA;
    Bm += (long)bz * sB;
    C += (long)bz * sC;
    if constexpr (ADDC) Cadd += (long)bz * sC;

    float acc[TM][TM];
#pragma unroll
    for (int i = 0; i < TM; ++i)
#pragma unroll
        for (int j = 0; j < TM; ++j) acc[i][j] = 0.f;

    for (int k0 = 0; k0 < Kd; k0 += BK) {
        // ---- A tile: TSZ rows x 16 k ----
#pragma unroll
        for (int u = 0; u < NL; ++u) {
            const int f = tid + u * 256;
            const int r = f >> 2;             // 0..TSZ-1
            const int k4 = (f & 3) * 4;
            const int gk = k0 + k4;
            float v0 = 0.f, v1 = 0.f, v2 = 0.f, v3 = 0.f;
            const int gr = rowBase + r;
            if (gr < M) {
                if constexpr (AMODE == 0) {
                    const float* p = A + (long)gr * lda + gk;
                    if (gk + 3 < Kd) {
                        float4 v = *(const float4*)p;
                        v0 = v.x; v1 = v.y; v2 = v.z; v3 = v.w;
                    } else {
                        if (gk + 0 < Kd) v0 = p[0];
                        if (gk + 1 < Kd) v1 = p[1];
                        if (gk + 2 < Kd) v2 = p[2];
                    }
                } else if constexpr (AMODE == 1) {
                    const int y = rIdx[gr];
                    const int s = rS[gr];
                    const float4 a = *(const float4*)(A  + (long)y * D_ + gk);
                    const float4 p = *(const float4*)(A2 + (long)s * D_ + gk);
                    v0 = a.x + p.x; v1 = a.y + p.y; v2 = a.z + p.z; v3 = a.w + p.w;
                } else {
                    if (gk < D_) {
                        const int nx = rIdx[gr];
                        const float4 a = *(const float4*)(A + (long)nx * D_ + gk);
                        v0 = a.x; v1 = a.y; v2 = a.z; v3 = a.w;
                    } else {
                        const float4 a = *(const float4*)(A2 + (long)gr * HID_ + (gk - D_));
                        v0 = a.x; v1 = a.y; v2 = a.z; v3 = a.w;
                    }
                }
            }
            As[k4 + 0][r] = v0; As[k4 + 1][r] = v1;
            As[k4 + 2][r] = v2; As[k4 + 3][r] = v3;
        }
        // ---- B tile ----
        if constexpr (!TB) {
#pragma unroll
            for (int u = 0; u < NL; ++u) {
                const int f = tid + u * 256;
                const int kk = f >> SHB;
                const int n4 = (f & NF4M) * 4;
                const int gk = k0 + kk;
                const int gc = colBase + n4;
                float v0 = 0.f, v1 = 0.f, v2 = 0.f, v3 = 0.f;
                if (gk < Kd) {
                    const float* p = Bm + (long)gk * ldb + gc;
                    if (gc + 3 < N) {
                        float4 v = *(const float4*)p;
                        v0 = v.x; v1 = v.y; v2 = v.z; v3 = v.w;
                    } else {
                        if (gc + 0 < N) v0 = p[0];
                        if (gc + 1 < N) v1 = p[1];
                        if (gc + 2 < N) v2 = p[2];
                        if (gc + 3 < N) v3 = p[3];
                    }
                }
                Bs[kk][n4 + 0] = v0; Bs[kk][n4 + 1] = v1;
                Bs[kk][n4 + 2] = v2; Bs[kk][n4 + 3] = v3;
            }
        } else {
#pragma unroll
            for (int u = 0; u < NL; ++u) {
                const int f = tid + u * 256;
                const int n = f >> 2;
                const int k4 = (f & 3) * 4;
                float v0 = 0.f, v1 = 0.f, v2 = 0.f, v3 = 0.f;
                const int gn = colBase + n;
                if (gn < N) {
                    const float* p = Bm + (long)gn * ldb + k0 + k4;
                    if (k0 + k4 + 3 < Kd) {
                        float4 v = *(const float4*)p;
                        v0 = v.x; v1 = v.y; v2 = v.z; v3 = v.w;
                    } else {
                        if (k0 + k4 + 0 < Kd) v0 = p[0];
                        if (k0 + k4 + 1 < Kd) v1 = p[1];
                        if (k0 + k4 + 2 < Kd) v2 = p[2];
                        if (k0 + k4 + 3 < Kd) v3 = p[3];
                    }
                }
                Bs[k4 + 0][n] = v0; Bs[k4 + 1][n] = v1;
                Bs[k4 + 2][n] = v2; Bs[k4 + 3][n] = v3;
            }
        }
        __syncthreads();

#pragma unroll
        for (int kk = 0; kk < BK; ++kk) {
            float a[TM], b[TM];
#pragma unroll
            for (int ih = 0; ih < TM / 4; ++ih) {
                *(float4*)&a[ih * 4] = *(const float4*)&As[kk][ih * 64 + ty * 4];
                *(float4*)&b[ih * 4] = *(const float4*)&Bs[kk][ih * 64 + tx * 4];
            }
#pragma unroll
            for (int i = 0; i < TM; ++i)
#pragma unroll
                for (int j = 0; j < TM; ++j)
                    acc[i][j] = fmaf(a[i], b[j], acc[i][j]);
        }
        __syncthreads();
    }

    // ---- epilogue (split-group index mapping) ----
#pragma unroll
    for (int i = 0; i < TM; ++i) {
        const int r = rowBase + (i >> 2) * 64 + ty * 4 + (i & 3);
        if (r >= M) continue;
#pragma unroll
        for (int j = 0; j < TM; ++j) {
            const int c = colBase + (j >> 2) * 64 + tx * 4 + (j & 3);
            if (c >= N) continue;
            float v = acc[i][j] * alpha;
            if constexpr (BIAS) v += bias[c];
            if constexpr (ADDC) v += Cadd[(long)r * ldc + c];
            if constexpr (RELU) v = fmaxf(v, 0.f);
            const long idx = (long)r * ldc + c;
            if constexpr (ACCUM) C[idx] += v; else C[idx] = v;
        }
    }
}

// ---------------- softmax over key axis with batch-index mask ----------------
__global__ __launch_bounds__(256) void softmax_k(float* __restrict__ Sc)
{
    const int row = blockIdx.x;
    const int b = row / S_;
    float* s = Sc + (long)row * SLD_;
    __shared__ float buf[S_];
    __shared__ float sm[5];
    const int klo = b - 1;

    float m = -3.4e38f;
    for (int k = threadIdx.x; k < S_; k += 256) {
        float v = s[k];
        if (k < klo) v -= 1e5f;
        buf[k] = v;
        m = fmaxf(m, v);
    }
    m = blk_reduce_max(m, sm);
    float sum = 0.f;
    for (int k = threadIdx.x; k < S_; k += 256) {
        const float e = __expf(buf[k] - m);
        buf[k] = e;
        sum += e;
    }
    sum = blk_reduce_sum(sum, sm);
    const float inv = 1.0f / sum;
    for (int k = threadIdx.x; k < S_; k += 256) s[k] = buf[k] * inv;
}

// ---------------- layernorm + final projection ----------------
__global__ __launch_bounds__(256) void final_k(
    const float* __restrict__ h, const float* __restrict__ g,
    const float* __restrict__ bt, const float* __restrict__ fw,
    const float* __restrict__ fb, float* __restrict__ out)
{
    const int row = blockIdx.x;
    const float* hr = h + (long)row * D_;
    __shared__ float sm[5];

    float lsum = 0.f;
    for (int d = threadIdx.x; d < D_; d += 256) lsum += hr[d];
    const float mu = blk_reduce_sum(lsum, sm) * (1.0f / D_);

    float lvar = 0.f;
    for (int d = threadIdx.x; d < D_; d += 256) {
        const float t = hr[d] - mu;
        lvar = fmaf(t, t, lvar);
    }
    const float var = blk_reduce_sum(lvar, sm) * (1.0f / D_);
    const float rstd = 1.0f / sqrtf(var + EPS_);

    float ldot = 0.f;
    for (int d = threadIdx.x; d < D_; d += 256) {
        const float zn = (hr[d] - mu) * rstd * g[d] + bt[d];
        ldot = fmaf(zn, fw[d], ldot);
    }
    const float dot = blk_reduce_sum(ldot, sm);
    if (threadIdx.x == 0) out[row] = dot + fb[0];
}

// ---------------- host launch ----------------
static inline dim3 ggrid(int M, int N, int batch, int tsz) {
    return dim3((N + tsz - 1) / tsz, (M + tsz - 1) / tsz, batch);
}

extern "C" void kernel_launch(void* const* d_in, const int* in_sizes, int n_in,
                              void* d_out, int out_size, void* d_ws, size_t ws_size,
                              hipStream_t stream)
{
    float* out = (float*)d_out;
    if (ws_size < WS_NEED_BYTES) {
        sentinel_k<<<(out_size + 255) / 256, 256, 0, stream>>>(out, out_size);
        return;
    }

    const int*   cate_x   = (const int*)  d_in[0];
    const float* cont_x   = (const float*)d_in[1];
    const int*   targets  = (const int*)  d_in[3];
    const float* M_emb    = (const float*)d_in[4];
    const float* E_emb    = (const float*)d_in[5];
    const float* pos_emb  = (const float*)d_in[6];
    const float* cate_emb = (const float*)d_in[7];
    const float* cont_W   = (const float*)d_in[8];
    const float* cont_b   = (const float*)d_in[9];
    const float* WQ = (const float*)d_in[10];
    const float* bQ = (const float*)d_in[11];
    const float* WK = (const float*)d_in[12];
    const float* bK = (const float*)d_in[13];
    const float* WV = (const float*)d_in[14];
    const float* bV = (const float*)d_in[15];
    const float* W0 = (const float*)d_in[16];
    const float* ln_g = (const float*)d_in[17];
    const float* ln_b = (const float*)d_in[18];
    const float* W1 = (const float*)d_in[19];
    const float* b1 = (const float*)d_in[20];
    const float* W2 = (const float*)d_in[21];
    const float* b2 = (const float*)d_in[22];
    const float* fw = (const float*)d_in[23];
    const float* fb = (const float*)d_in[24];
    float* ws  = (float*)d_ws;

    float* comb  = ws;
    int*   yArr  = (int*)(ws + COMB_SZ);
    int*   nxArr = yArr + BSR_;
    int*   sArr  = nxArr + BSR_;
    float* Qh = ws + COMB_SZ + IDX_PAD;
    float* Kh = Qh + QKV_SZ;
    float* Vh = Kh + QKV_SZ;
    float* Sc = Vh + QKV_SZ;
    float* Zo = Sc + SC_SZ;
    float* Zh   = Qh;   // alias: Q dead after QK^T
    float* Hid  = Qh;   // alias (FFN): BSR*768 fits in Qh+Kh span
    float* Hbuf = Sc;   // alias (FFN): BSR*768 fits in Sc span

    prep_k<<<(int)BSR_, 256, 0, stream>>>(cate_x, cont_x, targets, cate_emb,
                                          cont_W, cont_b, yArr, nxArr, sArr, comb);

    const float inv_sqrt_dh = 0.044194173824159216f;

    for (int h = 0; h < H_; ++h) {
        // Q = M_hat @ WQ[h] + bQ[h]  (64-tile, grid 8x256 = 2048 blocks)
        sgemm_k<64, 1, false, true, false, false, false, false>
            <<<ggrid((int)BSR_, DH_, 1, 64), 256, 0, stream>>>(
            M_emb, pos_emb, yArr, sArr,
            WQ + (long)h * D_ * DH_, nullptr, bQ + (long)h * DH_, nullptr,
            nullptr, Qh, nullptr,
            (int)BSR_, DH_, D_, D_, DH_, DH_, 0, 0, 0, 1.0f);
        // [K|V] = E_hat @ [WK[h]|WV[h]] + [bK|bV]  (fused, grid 16x256 = 4096)
        sgemm_k<64, 2, false, true, false, false, false, true>
            <<<ggrid((int)BSR_, 2 * DH_, 1, 64), 256, 0, stream>>>(
            E_emb, comb, nxArr, nullptr,
            WK + (long)h * (D_ + HID_) * DH_, WV + (long)h * (D_ + HID_) * DH_,
            bK + (long)h * DH_, bV + (long)h * DH_,
            nullptr, Kh, Vh,
            (int)BSR_, 2 * DH_, D_ + HID_, 0, DH_, DH_, 0, 0, 0, 1.0f);
        // scores = (1/sqrt(DH)) * Q @ K^T  (128-tile, grid 8x8x16 = 1024)
        sgemm_k<128, 0, true, false, false, false, false, false>
            <<<ggrid(S_, S_, B_, 128), 256, 0, stream>>>(
            Qh, nullptr, nullptr, nullptr,
            Kh, nullptr, nullptr, nullptr,
            nullptr, Sc, nullptr,
            S_, S_, DH_, DH_, DH_, SLD_,
            (long)S_ * DH_, (long)S_ * DH_, (long)S_ * SLD_, inv_sqrt_dh);
        softmax_k<<<(int)BSR_, 256, 0, stream>>>(Sc);
        // Z = P @ V  (64-tile, grid 8x16x16 = 2048)
        sgemm_k<64, 0, false, false, false, false, false, false>
            <<<ggrid(S_, DH_, B_, 64), 256, 0, stream>>>(
            Sc, nullptr, nullptr, nullptr,
            Vh, nullptr, nullptr, nullptr,
            nullptr, Zh, nullptr,
            S_, DH_, S_, SLD_, DH_, DH_,
            (long)S_ * SLD_, (long)S_ * DH_, (long)S_ * DH_, 1.0f);
        // z (+)= Z_h @ W0[h]  (64-tile, grid 12x256 = 3072)
        if (h == 0)
            sgemm_k<64, 0, false, false, false, false, false, false>
                <<<ggrid((int)BSR_, D_, 1, 64), 256, 0, stream>>>(
                Zh, nullptr, nullptr, nullptr,
                W0 + (long)h * DH_ * D_, nullptr, nullptr, nullptr,
                nullptr, Zo, nullptr,
                (int)BSR_, D_, DH_, DH_, D_, D_, 0, 0, 0, 1.0f);
        else
            sgemm_k<64, 0, false, false, false, false, true, false>
                <<<ggrid((int)BSR_, D_, 1, 64), 256, 0, stream>>>(
                Zh, nullptr, nullptr, nullptr,
                W0 + (long)h * DH_ * D_, nullptr, nullptr, nullptr,
                nullptr, Zo, nullptr,
                (int)BSR_, D_, DH_, DH_, D_, D_, 0, 0, 0, 1.0f);
    }

    // FFN in 4 chunks of 768 FF-columns
    for (int c = 0; c < 4; ++c) {
        const int f0 = c * 768;
        sgemm_k<64, 0, false, true, true, false, false, false>
            <<<ggrid((int)BSR_, 768, 1, 64), 256, 0, stream>>>(
            Zo, nullptr, nullptr, nullptr,
            W1 + f0, nullptr, b1 + f0, nullptr,
            nullptr, Hid, nullptr,
            (int)BSR_, 768, D_, D_, FF_, 768, 0, 0, 0, 1.0f);
        if (c == 0)
            sgemm_k<64, 0, false, true, false, true, false, false>
                <<<ggrid((int)BSR_, D_, 1, 64), 256, 0, stream>>>(
                Hid, nullptr, nullptr, nullptr,
                W2 + (long)f0 * D_, nullptr, b2, nullptr,
                Zo, Hbuf, nullptr,
                (int)BSR_, D_, 768, 768, D_, D_, 0, 0, 0, 1.0f);
        else
            sgemm_k<64, 0, false, false, false, false, true, false>
                <<<ggrid((int)BSR_, D_, 1, 64), 256, 0, stream>>>(
                Hid, nullptr, nullptr, nullptr,
                W2 + (long)f0 * D_, nullptr, nullptr, nullptr,
                nullptr, Hbuf, nullptr,
                (int)BSR_, D_, 768, 768, D_, D_, 0, 0, 0, 1.0f);
    }

    final_k<<<(int)BSR_, 256, 0, stream>>>(Hbuf, ln_g, ln_b, fw, fb, out);

    (void)in_sizes; (void)n_in;
}

// Round 10
// 11949.968 us; speedup vs baseline: 1.0896x; 1.0821x over previous
//
#include <hip/hip_runtime.h>
#include <hip/hip_bf16.h>

// ---------------- problem constants ----------------
constexpr int B_   = 16;
constexpr int L_   = 1024;
constexpr int S_   = 1023;      // L-1
constexpr int D_   = 768;
constexpr int H_   = 8;
constexpr int DH_  = 512;       // D/3*2
constexpr int HID_ = 256;
constexpr int FF_  = 3072;
constexpr int NA_  = 10000;
constexpr int NCATE_ = 4;
constexpr int NCONT_ = 6;
constexpr float EPS_ = 1e-5f;
constexpr long BSR_ = (long)B_ * S_;    // 16368 rows
constexpr int SLD_ = 1024;              // score row stride (fp32 units)
constexpr int SLD2_ = 2048;             // score row stride (bf16 units): hi[0..1023] lo[1024..2047]
constexpr int VTLD_ = 1024;             // VT row stride (bf16, padded from 1023)

// workspace layout (floats) — 58,720,256 floats = 234,881,024 B ≈ 224.03 MiB
constexpr long COMB_SZ = BSR_ * HID_;            //  4,190,208
constexpr long IDX_PAD = 49152;
constexpr long QB_F  = BSR_ * DH_ / 2;           //  4,190,208 (bf16 Q)
constexpr long KB_F  = BSR_ * DH_ / 2;           //  4,190,208 (bf16 K)
constexpr long VTH_F = (long)B_ * DH_ * VTLD_ / 2; // 4,194,304 (bf16 VT hi)
constexpr long VTL_F = VTH_F;                    //  4,194,304 (bf16 VT lo)
constexpr long SC_SZ = (long)B_ * S_ * SLD_;     // 16,760,832
constexpr long ZH_SZ = BSR_ * DH_;               //  8,380,416 (fp32 Z)
constexpr long ZO_SZ = BSR_ * D_;                // 12,570,624
constexpr size_t WS_NEED_BYTES =
    (size_t)(COMB_SZ + IDX_PAD + QB_F + KB_F + VTH_F + VTL_F + SC_SZ + ZH_SZ + ZO_SZ) * 4;

typedef __attribute__((ext_vector_type(8))) short bf16x8;
typedef __attribute__((ext_vector_type(4))) float f32x4;

// ---------------- block reductions ----------------
__device__ __forceinline__ float blk_reduce_sum(float v, float* sm) {
#pragma unroll
    for (int off = 32; off > 0; off >>= 1) v += __shfl_down(v, off, 64);
    const int lane = threadIdx.x & 63, wv = threadIdx.x >> 6;
    if (lane == 0) sm[wv] = v;
    __syncthreads();
    float t = (threadIdx.x < 4) ? sm[threadIdx.x] : 0.f;
    t += __shfl_down(t, 2, 64);
    t += __shfl_down(t, 1, 64);
    if (threadIdx.x == 0) sm[4] = t;
    __syncthreads();
    float r = sm[4];
    __syncthreads();
    return r;
}

__device__ __forceinline__ float blk_reduce_max(float v, float* sm) {
#pragma unroll
    for (int off = 32; off > 0; off >>= 1) v = fmaxf(v, __shfl_down(v, off, 64));
    const int lane = threadIdx.x & 63, wv = threadIdx.x >> 6;
    if (lane == 0) sm[wv] = v;
    __syncthreads();
    float t = (threadIdx.x < 4) ? sm[threadIdx.x] : -3.4e38f;
    t = fmaxf(t, __shfl_down(t, 2, 64));
    t = fmaxf(t, __shfl_down(t, 1, 64));
    if (threadIdx.x == 0) sm[4] = t;
    __syncthreads();
    float r = sm[4];
    __syncthreads();
    return r;
}

// ---------------- ws-too-small sentinel ----------------
__global__ __launch_bounds__(256) void sentinel_k(float* __restrict__ out, int n)
{
    const int i = blockIdx.x * 256 + threadIdx.x;
    if (i < n) out[i] = 1e30f;
}

// ---------------- prep: row indices + comb ----------------
__global__ __launch_bounds__(256) void prep_k(
    const int* __restrict__ cate_x, const float* __restrict__ cont_x,
    const int* __restrict__ targets,
    const float* __restrict__ cate_emb, const float* __restrict__ cont_W,
    const float* __restrict__ cont_b,
    int* __restrict__ yArr, int* __restrict__ nxArr, int* __restrict__ sArr,
    float* __restrict__ comb)
{
    const int row = blockIdx.x;          // b*S + s
    const int b = row / S_;
    const int s = row - b * S_;
    const int nx = cate_x[((long)b * L_ + s + 1) * NCATE_];
    if (threadIdx.x == 0) {
        yArr[row]  = cate_x[((long)b * L_ + s) * NCATE_] + targets[(long)b * L_ + s] * NA_;
        nxArr[row] = nx;
        sArr[row]  = s;
    }
    const float* cx = cont_x + ((long)b * L_ + s + 1) * NCONT_;
    float cv[NCONT_];
#pragma unroll
    for (int i = 0; i < NCONT_; ++i) cv[i] = cx[i];
    const int j = threadIdx.x;
    float acc = cont_b[j];
#pragma unroll
    for (int i = 0; i < NCONT_; ++i) acc = fmaf(cv[i], cont_W[i * HID_ + j], acc);
    comb[(long)row * HID_ + j] = cate_emb[(long)nx * HID_ + j] + acc;
}

// ---------------- tiled fp32 GEMM (64-tile), fp32 or bf16 output ----------------
// AMODE 0: plain A (lda);  1: A-row = M_emb[yArr[r]] + pos_emb[sArr[r]] (Kd=768)
//                          2: A-row = [E_emb[nxArr[r]] | comb[r]]       (Kd=1024)
// KVF: blocks with colBase>=DH_ are V blocks -> {Bm2,bias2}, output hi/lo transposed.
// OMODE 0: fp32 C (ldc, optional ACCUM/ADDC). OMODE 1: bf16 CbA row-major (ldc);
//          V blocks write VT_hi/VT_lo: [bb][c][rl], stride VTLD_.
template<int AMODE, bool BIAS, bool RELU, bool ADDC, bool ACCUM, bool KVF, int OMODE>
__global__ __launch_bounds__(256) void sgemm_k(
    const float* __restrict__ A, const float* __restrict__ A2,
    const int* __restrict__ rIdx, const int* __restrict__ rS,
    const float* __restrict__ Bm, const float* __restrict__ Bm2,
    const float* __restrict__ bias, const float* __restrict__ bias2,
    const float* __restrict__ Cadd, float* __restrict__ C,
    short* __restrict__ CbA, short* __restrict__ CbVh, short* __restrict__ CbVl,
    int M, int N, int Kd, int lda, int ldb, int ldc,
    long sA, long sB, long sC, float alpha)
{
    constexpr int BK = 16;
    constexpr int TSZ = 64, TM = 4;
    __shared__ float As[BK][TSZ];
    __shared__ float Bs[BK][TSZ];

    const int tid = threadIdx.x;
    const int tx = tid & 15;
    const int ty = tid >> 4;
    const int rowBase = blockIdx.y * TSZ;
    int colBase = blockIdx.x * TSZ;
    const int bz = blockIdx.z;
    bool isV = false;

    if constexpr (KVF) {
        if (colBase >= DH_) {
            Bm = Bm2;
            if constexpr (BIAS) bias = bias2;
            colBase -= DH_;
            isV = true;
        }
    }
    if constexpr (AMODE == 0) A += (long)bz * sA;
    Bm += (long)bz * sB;
    C += (long)bz * sC;
    if constexpr (ADDC) Cadd += (long)bz * sC;

    float acc[TM][TM];
#pragma unroll
    for (int i = 0; i < TM; ++i)
#pragma unroll
        for (int j = 0; j < TM; ++j) acc[i][j] = 0.f;

    for (int k0 = 0; k0 < Kd; k0 += BK) {
        // ---- A tile ----
        {
            const int f = tid;
            const int r = f >> 2;
            const int k4 = (f & 3) * 4;
            const int gk = k0 + k4;
            float v0 = 0.f, v1 = 0.f, v2 = 0.f, v3 = 0.f;
            const int gr = rowBase + r;
            if (gr < M) {
                if constexpr (AMODE == 0) {
                    const float* p = A + (long)gr * lda + gk;
                    if (gk + 3 < Kd) {
                        float4 v = *(const float4*)p;
                        v0 = v.x; v1 = v.y; v2 = v.z; v3 = v.w;
                    } else {
                        if (gk + 0 < Kd) v0 = p[0];
                        if (gk + 1 < Kd) v1 = p[1];
                        if (gk + 2 < Kd) v2 = p[2];
                    }
                } else if constexpr (AMODE == 1) {
                    const int y = rIdx[gr];
                    const int s = rS[gr];
                    const float4 a = *(const float4*)(A  + (long)y * D_ + gk);
                    const float4 p = *(const float4*)(A2 + (long)s * D_ + gk);
                    v0 = a.x + p.x; v1 = a.y + p.y; v2 = a.z + p.z; v3 = a.w + p.w;
                } else {
                    if (gk < D_) {
                        const int nx = rIdx[gr];
                        const float4 a = *(const float4*)(A + (long)nx * D_ + gk);
                        v0 = a.x; v1 = a.y; v2 = a.z; v3 = a.w;
                    } else {
                        const float4 a = *(const float4*)(A2 + (long)gr * HID_ + (gk - D_));
                        v0 = a.x; v1 = a.y; v2 = a.z; v3 = a.w;
                    }
                }
            }
            As[k4 + 0][r] = v0; As[k4 + 1][r] = v1;
            As[k4 + 2][r] = v2; As[k4 + 3][r] = v3;
        }
        // ---- B tile (Kd x N row-major) ----
        {
            const int f = tid;
            const int kk = f >> 4;
            const int n4 = (f & 15) * 4;
            const int gk = k0 + kk;
            const int gc = colBase + n4;
            float v0 = 0.f, v1 = 0.f, v2 = 0.f, v3 = 0.f;
            if (gk < Kd) {
                const float* p = Bm + (long)gk * ldb + gc;
                if (gc + 3 < N) {
                    float4 v = *(const float4*)p;
                    v0 = v.x; v1 = v.y; v2 = v.z; v3 = v.w;
                } else {
                    if (gc + 0 < N) v0 = p[0];
                    if (gc + 1 < N) v1 = p[1];
                    if (gc + 2 < N) v2 = p[2];
                    if (gc + 3 < N) v3 = p[3];
                }
            }
            Bs[kk][n4 + 0] = v0; Bs[kk][n4 + 1] = v1;
            Bs[kk][n4 + 2] = v2; Bs[kk][n4 + 3] = v3;
        }
        __syncthreads();

#pragma unroll
        for (int kk = 0; kk < BK; ++kk) {
            float a[TM], b[TM];
            *(float4*)&a[0] = *(const float4*)&As[kk][ty * 4];
            *(float4*)&b[0] = *(const float4*)&Bs[kk][tx * 4];
#pragma unroll
            for (int i = 0; i < TM; ++i)
#pragma unroll
                for (int j = 0; j < TM; ++j)
                    acc[i][j] = fmaf(a[i], b[j], acc[i][j]);
        }
        __syncthreads();
    }

    // ---- epilogue ----
#pragma unroll
    for (int i = 0; i < TM; ++i) {
        const int r = rowBase + ty * 4 + i;
        if (r >= M) continue;
        const int bb = r / S_;
        const int rl = r - bb * S_;
#pragma unroll
        for (int j = 0; j < TM; ++j) {
            const int c = colBase + tx * 4 + j;
            if (c >= N) continue;
            float v = acc[i][j] * alpha;
            if constexpr (BIAS) v += bias[c];
            if constexpr (ADDC) v += Cadd[(long)r * ldc + c];
            if constexpr (RELU) v = fmaxf(v, 0.f);
            if constexpr (OMODE == 0) {
                const long idx = (long)r * ldc + c;
                if constexpr (ACCUM) C[idx] += v; else C[idx] = v;
            } else {
                const __hip_bfloat16 hv = __float2bfloat16(v);
                if (KVF && isV) {
                    const long vidx = ((long)bb * DH_ + c) * VTLD_ + rl;
                    ((__hip_bfloat16*)CbVh)[vidx] = hv;
                    ((__hip_bfloat16*)CbVl)[vidx] =
                        __float2bfloat16(v - __bfloat162float(hv));
                } else {
                    ((__hip_bfloat16*)CbA)[(long)r * ldc + c] = hv;
                }
            }
        }
    }
}

// ---------------- QK^T via MFMA (bf16 in, fp32 scores out) ----------------
// block = 4 waves, each wave a 32x32 tile; block tile 64x64.
__global__ __launch_bounds__(256) void qkt_mfma_k(
    const short* __restrict__ Qb, const short* __restrict__ Kb,
    float* __restrict__ Sc, float alpha)
{
    const int b  = blockIdx.z;
    const int qT = blockIdx.y * 64;
    const int kT = blockIdx.x * 64;
    const int w  = threadIdx.x >> 6;
    const int l  = threadIdx.x & 63;
    const int q0 = qT + (w >> 1) * 32;
    const int k0 = kT + (w & 1) * 32;
    const int lr = l & 15;
    const int lk = (l >> 4) * 8;

    const short* qp0 = Qb + ((long)b * S_ + q0 + lr) * DH_ + lk;
    const short* qp1 = qp0 + 16 * DH_;
    const short* kp0 = Kb + ((long)b * S_ + k0 + lr) * DH_ + lk;
    const short* kp1 = kp0 + 16 * DH_;

    f32x4 acc00 = {0.f,0.f,0.f,0.f}, acc01 = acc00, acc10 = acc00, acc11 = acc00;
#pragma unroll 4
    for (int d = 0; d < DH_; d += 32) {
        bf16x8 a0 = *(const bf16x8*)(qp0 + d);
        bf16x8 a1 = *(const bf16x8*)(qp1 + d);
        bf16x8 b0 = *(const bf16x8*)(kp0 + d);
        bf16x8 b1 = *(const bf16x8*)(kp1 + d);
        acc00 = __builtin_amdgcn_mfma_f32_16x16x32_bf16(a0, b0, acc00, 0, 0, 0);
        acc01 = __builtin_amdgcn_mfma_f32_16x16x32_bf16(a0, b1, acc01, 0, 0, 0);
        acc10 = __builtin_amdgcn_mfma_f32_16x16x32_bf16(a1, b0, acc10, 0, 0, 0);
        acc11 = __builtin_amdgcn_mfma_f32_16x16x32_bf16(a1, b1, acc11, 0, 0, 0);
    }

    float* sc = Sc + (long)b * S_ * SLD_;
    const int rbase = (l >> 4) * 4;     // C/D row = (lane>>4)*4 + reg  [m89]
#pragma unroll
    for (int mi = 0; mi < 2; ++mi) {
#pragma unroll
        for (int ni = 0; ni < 2; ++ni) {
            const f32x4 av = (mi == 0) ? (ni == 0 ? acc00 : acc01)
                                       : (ni == 0 ? acc10 : acc11);
            const int kk = k0 + ni * 16 + lr;   // C/D col = lane&15
            if (kk >= S_) continue;
#pragma unroll
            for (int i = 0; i < 4; ++i) {
                const int qq = q0 + mi * 16 + rbase + i;
                if (qq < S_) sc[(long)qq * SLD_ + kk] = av[i] * alpha;
            }
        }
    }
}

// ---------------- PV via MFMA, split-precision P and V ----------------
// Z[b*S+q][e] = sum_k P[q][k] * VT[e][k], P ~= Ph+Pl, V ~= Vh+Vl;
// acc += Ph*Vh + Ph*Vl + Pl*Vh  (lo*lo dropped)
__global__ __launch_bounds__(256) void pv_mfma_k(
    const short* __restrict__ Pb, const short* __restrict__ VTh,
    const short* __restrict__ VTl, float* __restrict__ Z)
{
    const int b  = blockIdx.z;
    const int qT = blockIdx.y * 64;
    const int eT = blockIdx.x * 64;
    const int w  = threadIdx.x >> 6;
    const int l  = threadIdx.x & 63;
    const int q0 = qT + (w >> 1) * 32;
    const int e0 = eT + (w & 1) * 32;
    const int lr = l & 15;
    const int lk = (l >> 4) * 8;

    const short* pp0 = Pb + ((long)b * S_ + q0 + lr) * SLD2_ + lk;
    const short* pp1 = pp0 + 16 * SLD2_;
    const long voff = (long)b * DH_ * VTLD_ + (long)(e0 + lr) * VTLD_ + lk;
    const short* vh0 = VTh + voff;
    const short* vh1 = vh0 + 16 * VTLD_;
    const short* vl0 = VTl + voff;
    const short* vl1 = vl0 + 16 * VTLD_;

    f32x4 acc00 = {0.f,0.f,0.f,0.f}, acc01 = acc00, acc10 = acc00, acc11 = acc00;
#pragma unroll 2
    for (int k = 0; k < 1024; k += 32) {
        bf16x8 ah0 = *(const bf16x8*)(pp0 + k);
        bf16x8 al0 = *(const bf16x8*)(pp0 + 1024 + k);
        bf16x8 ah1 = *(const bf16x8*)(pp1 + k);
        bf16x8 al1 = *(const bf16x8*)(pp1 + 1024 + k);
        bf16x8 bh0 = *(const bf16x8*)(vh0 + k);
        bf16x8 bl0 = *(const bf16x8*)(vl0 + k);
        bf16x8 bh1 = *(const bf16x8*)(vh1 + k);
        bf16x8 bl1 = *(const bf16x8*)(vl1 + k);
        acc00 = __builtin_amdgcn_mfma_f32_16x16x32_bf16(ah0, bh0, acc00, 0, 0, 0);
        acc00 = __builtin_amdgcn_mfma_f32_16x16x32_bf16(ah0, bl0, acc00, 0, 0, 0);
        acc00 = __builtin_amdgcn_mfma_f32_16x16x32_bf16(al0, bh0, acc00, 0, 0, 0);
        acc01 = __builtin_amdgcn_mfma_f32_16x16x32_bf16(ah0, bh1, acc01, 0, 0, 0);
        acc01 = __builtin_amdgcn_mfma_f32_16x16x32_bf16(ah0, bl1, acc01, 0, 0, 0);
        acc01 = __builtin_amdgcn_mfma_f32_16x16x32_bf16(al0, bh1, acc01, 0, 0, 0);
        acc10 = __builtin_amdgcn_mfma_f32_16x16x32_bf16(ah1, bh0, acc10, 0, 0, 0);
        acc10 = __builtin_amdgcn_mfma_f32_16x16x32_bf16(ah1, bl0, acc10, 0, 0, 0);
        acc10 = __builtin_amdgcn_mfma_f32_16x16x32_bf16(al1, bh0, acc10, 0, 0, 0);
        acc11 = __builtin_amdgcn_mfma_f32_16x16x32_bf16(ah1, bh1, acc11, 0, 0, 0);
        acc11 = __builtin_amdgcn_mfma_f32_16x16x32_bf16(ah1, bl1, acc11, 0, 0, 0);
        acc11 = __builtin_amdgcn_mfma_f32_16x16x32_bf16(al1, bh1, acc11, 0, 0, 0);
    }

    float* z = Z + (long)b * S_ * DH_;
    const int rbase = (l >> 4) * 4;
#pragma unroll
    for (int mi = 0; mi < 2; ++mi) {
#pragma unroll
        for (int ni = 0; ni < 2; ++ni) {
            const f32x4 av = (mi == 0) ? (ni == 0 ? acc00 : acc01)
                                       : (ni == 0 ? acc10 : acc11);
            const int ee = e0 + ni * 16 + lr;
#pragma unroll
            for (int i = 0; i < 4; ++i) {
                const int qq = q0 + mi * 16 + rbase + i;
                if (qq < S_) z[(long)qq * DH_ + ee] = av[i];
            }
        }
    }
}

// ---------------- softmax (fp32 in, split bf16 P out in-place) ----------------
__global__ __launch_bounds__(256) void softmax_k(float* __restrict__ Sc)
{
    const int row = blockIdx.x;
    const int b = row / S_;
    float* s = Sc + (long)row * SLD_;
    __shared__ float buf[S_];
    __shared__ float sm[5];
    const int klo = b - 1;

    float m = -3.4e38f;
    for (int k = threadIdx.x; k < S_; k += 256) {
        float v = s[k];
        if (k < klo) v -= 1e5f;
        buf[k] = v;
        m = fmaxf(m, v);
    }
    m = blk_reduce_max(m, sm);
    float sum = 0.f;
    for (int k = threadIdx.x; k < S_; k += 256) {
        const float e = __expf(buf[k] - m);
        buf[k] = e;
        sum += e;
    }
    sum = blk_reduce_sum(sum, sm);
    const float inv = 1.0f / sum;
    // in-place: hi at shorts [0..1023], lo at [1024..2047] of this row
    __hip_bfloat16* pb = reinterpret_cast<__hip_bfloat16*>(s);
    for (int k = threadIdx.x; k < S_; k += 256) {
        const float p = buf[k] * inv;
        const __hip_bfloat16 hi = __float2bfloat16(p);
        pb[k] = hi;
        pb[1024 + k] = __float2bfloat16(p - __bfloat162float(hi));
    }
    if (threadIdx.x == 0) {
        pb[S_] = __float2bfloat16(0.f);          // hi pad k=1023
        pb[1024 + S_] = __float2bfloat16(0.f);   // lo pad k=1023
    }
}

// ---------------- layernorm + final projection ----------------
__global__ __launch_bounds__(256) void final_k(
    const float* __restrict__ h, const float* __restrict__ g,
    const float* __restrict__ bt, const float* __restrict__ fw,
    const float* __restrict__ fb, float* __restrict__ out)
{
    const int row = blockIdx.x;
    const float* hr = h + (long)row * D_;
    __shared__ float sm[5];

    float lsum = 0.f;
    for (int d = threadIdx.x; d < D_; d += 256) lsum += hr[d];
    const float mu = blk_reduce_sum(lsum, sm) * (1.0f / D_);

    float lvar = 0.f;
    for (int d = threadIdx.x; d < D_; d += 256) {
        const float t = hr[d] - mu;
        lvar = fmaf(t, t, lvar);
    }
    const float var = blk_reduce_sum(lvar, sm) * (1.0f / D_);
    const float rstd = 1.0f / sqrtf(var + EPS_);

    float ldot = 0.f;
    for (int d = threadIdx.x; d < D_; d += 256) {
        const float zn = (hr[d] - mu) * rstd * g[d] + bt[d];
        ldot = fmaf(zn, fw[d], ldot);
    }
    const float dot = blk_reduce_sum(ldot, sm);
    if (threadIdx.x == 0) out[row] = dot + fb[0];
}

// ---------------- host launch ----------------
static inline dim3 ggrid(int M, int N, int batch, int tsz) {
    return dim3((N + tsz - 1) / tsz, (M + tsz - 1) / tsz, batch);
}

extern "C" void kernel_launch(void* const* d_in, const int* in_sizes, int n_in,
                              void* d_out, int out_size, void* d_ws, size_t ws_size,
                              hipStream_t stream)
{
    float* out = (float*)d_out;
    if (ws_size < WS_NEED_BYTES) {
        sentinel_k<<<(out_size + 255) / 256, 256, 0, stream>>>(out, out_size);
        return;
    }

    const int*   cate_x   = (const int*)  d_in[0];
    const float* cont_x   = (const float*)d_in[1];
    const int*   targets  = (const int*)  d_in[3];
    const float* M_emb    = (const float*)d_in[4];
    const float* E_emb    = (const float*)d_in[5];
    const float* pos_emb  = (const float*)d_in[6];
    const float* cate_emb = (const float*)d_in[7];
    const float* cont_W   = (const float*)d_in[8];
    const float* cont_b   = (const float*)d_in[9];
    const float* WQ = (const float*)d_in[10];
    const float* bQ = (const float*)d_in[11];
    const float* WK = (const float*)d_in[12];
    const float* bK = (const float*)d_in[13];
    const float* WV = (const float*)d_in[14];
    const float* bV = (const float*)d_in[15];
    const float* W0 = (const float*)d_in[16];
    const float* ln_g = (const float*)d_in[17];
    const float* ln_b = (const float*)d_in[18];
    const float* W1 = (const float*)d_in[19];
    const float* b1 = (const float*)d_in[20];
    const float* W2 = (const float*)d_in[21];
    const float* b2 = (const float*)d_in[22];
    const float* fw = (const float*)d_in[23];
    const float* fb = (const float*)d_in[24];
    float* ws  = (float*)d_ws;

    // arena
    float* comb  = ws;
    int*   yArr  = (int*)(ws + COMB_SZ);
    int*   nxArr = yArr + BSR_;
    int*   sArr  = nxArr + BSR_;
    float* bfA = ws + COMB_SZ + IDX_PAD;       // bf16 arena start
    short* Qb  = (short*)bfA;                  // [BSR][DH] bf16
    short* Kb  = Qb + BSR_ * DH_;              // [BSR][DH] bf16
    short* VTh = Kb + BSR_ * DH_;              // [B][DH][VTLD] bf16
    short* VTl = VTh + (long)B_ * DH_ * VTLD_; // [B][DH][VTLD] bf16
    float* Sc  = bfA + QB_F + KB_F + VTH_F + VTL_F;  // fp32 scores / bf16 P
    float* Zh  = Sc + SC_SZ;                   // fp32 Z
    float* Zo  = Zh + ZH_SZ;
    float* Hid  = bfA;   // FFN hidden aliases bf16 arena (dead in FFN phase)
    float* Hbuf = Sc;    // FFN output aliases Sc

    prep_k<<<(int)BSR_, 256, 0, stream>>>(cate_x, cont_x, targets, cate_emb,
                                          cont_W, cont_b, yArr, nxArr, sArr, comb);

    const float inv_sqrt_dh = 0.044194173824159216f;

    for (int h = 0; h < H_; ++h) {
        // Q = M_hat @ WQ[h] + bQ[h]  -> bf16 row-major
        sgemm_k<1, true, false, false, false, false, 1>
            <<<ggrid((int)BSR_, DH_, 1, 64), 256, 0, stream>>>(
            M_emb, pos_emb, yArr, sArr,
            WQ + (long)h * D_ * DH_, nullptr, bQ + (long)h * DH_, nullptr,
            nullptr, nullptr, Qb, nullptr, nullptr,
            (int)BSR_, DH_, D_, D_, DH_, DH_, 0, 0, 0, 1.0f);
        // [K|V]: K -> bf16 row-major; V -> split bf16 transposed per batch
        sgemm_k<2, true, false, false, false, true, 1>
            <<<ggrid((int)BSR_, 2 * DH_, 1, 64), 256, 0, stream>>>(
            E_emb, comb, nxArr, nullptr,
            WK + (long)h * (D_ + HID_) * DH_, WV + (long)h * (D_ + HID_) * DH_,
            bK + (long)h * DH_, bV + (long)h * DH_,
            nullptr, nullptr, Kb, VTh, VTl,
            (int)BSR_, 2 * DH_, D_ + HID_, 0, DH_, DH_, 0, 0, 0, 1.0f);
        // scores via MFMA
        qkt_mfma_k<<<dim3(16, 16, B_), 256, 0, stream>>>(Qb, Kb, Sc, inv_sqrt_dh);
        // softmax + in-place split-bf16 P
        softmax_k<<<(int)BSR_, 256, 0, stream>>>(Sc);
        // Z = P @ V via split-precision MFMA
        pv_mfma_k<<<dim3(8, 16, B_), 256, 0, stream>>>(
            (const short*)Sc, VTh, VTl, Zh);
        // z (+)= Z_h @ W0[h]
        if (h == 0)
            sgemm_k<0, false, false, false, false, false, 0>
                <<<ggrid((int)BSR_, D_, 1, 64), 256, 0, stream>>>(
                Zh, nullptr, nullptr, nullptr,
                W0 + (long)h * DH_ * D_, nullptr, nullptr, nullptr,
                nullptr, Zo, nullptr, nullptr, nullptr,
                (int)BSR_, D_, DH_, DH_, D_, D_, 0, 0, 0, 1.0f);
        else
            sgemm_k<0, false, false, false, true, false, 0>
                <<<ggrid((int)BSR_, D_, 1, 64), 256, 0, stream>>>(
                Zh, nullptr, nullptr, nullptr,
                W0 + (long)h * DH_ * D_, nullptr, nullptr, nullptr,
                nullptr, Zo, nullptr, nullptr, nullptr,
                (int)BSR_, D_, DH_, DH_, D_, D_, 0, 0, 0, 1.0f);
    }

    // FFN in 4 chunks of 768 FF-columns
    for (int c = 0; c < 4; ++c) {
        const int f0 = c * 768;
        sgemm_k<0, true, true, false, false, false, 0>
            <<<ggrid((int)BSR_, 768, 1, 64), 256, 0, stream>>>(
            Zo, nullptr, nullptr, nullptr,
            W1 + f0, nullptr, b1 + f0, nullptr,
            nullptr, Hid, nullptr, nullptr, nullptr,
            (int)BSR_, 768, D_, D_, FF_, 768, 0, 0, 0, 1.0f);
        if (c == 0)
            sgemm_k<0, true, false, true, false, false, 0>
                <<<ggrid((int)BSR_, D_, 1, 64), 256, 0, stream>>>(
                Hid, nullptr, nullptr, nullptr,
                W2 + (long)f0 * D_, nullptr, b2, nullptr,
                Zo, Hbuf, nullptr, nullptr, nullptr,
                (int)BSR_, D_, 768, 768, D_, D_, 0, 0, 0, 1.0f);
        else
            sgemm_k<0, false, false, false, true, false, 0>
                <<<ggrid((int)BSR_, D_, 1, 64), 256, 0, stream>>>(
                Hid, nullptr, nullptr, nullptr,
                W2 + (long)f0 * D_, nullptr, nullptr, nullptr,
                nullptr, Hbuf, nullptr, nullptr, nullptr,
                (int)BSR_, D_, 768, 768, D_, D_, 0, 0, 0, 1.0f);
    }

    final_k<<<(int)BSR_, 256, 0, stream>>>(Hbuf, ln_g, ln_b, fw, fb, out);

    (void)in_sizes; (void)n_in;
}